// Round 15
// baseline (214.023 us; speedup 1.0000x reference)
//
#include <hip/hip_runtime.h>
#include <cstdint>
#include <cstddef>

typedef unsigned short u16;
typedef unsigned int u32;
typedef __attribute__((ext_vector_type(4))) float f32x4;
typedef __attribute__((ext_vector_type(8))) __bf16 bf16x8;
typedef __attribute__((ext_vector_type(8))) u16 u16x8;
typedef __attribute__((ext_vector_type(4))) u16 u16x4;
typedef __attribute__((ext_vector_type(2))) u32 u32x2;

__device__ __forceinline__ u16 f2bf(float x) {
  u32 u = __builtin_bit_cast(u32, x);
  u += 0x7fffu + ((u >> 16) & 1u);
  return (u16)(u >> 16);
}
__device__ __forceinline__ float bf2f(u16 b) {
  return __builtin_bit_cast(float, (u32)b << 16);
}
__device__ __forceinline__ bf16x8 ldfrag(const u16* p) {
  return __builtin_bit_cast(bf16x8, *(const u16x8*)p);
}
__device__ __forceinline__ void gload_lds16(const void* g, void* l) {
  auto gp = (const __attribute__((address_space(1))) u32*)g;
  auto lp = (__attribute__((address_space(3))) u32*)l;
  __builtin_amdgcn_global_load_lds(gp, lp, 16, 0, 0);
}
#define MFMA16(a, b, c) __builtin_amdgcn_mfma_f32_16x16x32_bf16(a, b, c, 0, 0, 0)

// ---------------- fused prep: 3 bf16 converts + 3 transposed converts ----------------
__global__ void prep_kernel(const float* __restrict__ x, const float* __restrict__ qkr,
                            const float* __restrict__ vr, const float* __restrict__ qkw,
                            const float* __restrict__ vw, const float* __restrict__ wo,
                            u16* __restrict__ x_bf, u16* __restrict__ qkr_b,
                            u16* __restrict__ vr_b, u16* __restrict__ qkwT,
                            u16* __restrict__ vwT, u16* __restrict__ woT) {
  __shared__ float tile[32][33];
  const int bid = blockIdx.x;
  const int tid = threadIdx.x;
  if (bid < 10240) {  // element-wise f32 -> bf16
    const float* in;
    u16* out;
    int base;
    if (bid < 8192) { in = x; out = x_bf; base = bid; }
    else if (bid < 9216) { in = qkr; out = qkr_b; base = bid - 8192; }
    else { in = vr; out = vr_b; base = bid - 9216; }
    int i = base * 1024 + tid * 4;
    f32x4 v = *(const f32x4*)(in + i);
    u16x4 r = { f2bf(v[0]), f2bf(v[1]), f2bf(v[2]), f2bf(v[3]) };
    *(u16x4*)(out + i) = r;
  } else {  // 32x32 tiled transpose + bf16
    const float* in;
    u16* out;
    int R, C, local;
    if (bid < 11264) { in = qkw; out = qkwT; R = 512; C = 2048; local = bid - 10240; }
    else if (bid < 12288) { in = vw; out = vwT; R = 512; C = 2048; local = bid - 11264; }
    else { in = wo; out = woT; R = 2048; C = 2048; local = bid - 12288; }
    int bx = (local & 63) * 32, by = (local >> 6) * 32;
    int tx = tid & 31, ty = tid >> 5;
#pragma unroll
    for (int i = 0; i < 32; i += 8)
      tile[ty + i][tx] = in[(size_t)(by + ty + i) * C + bx + tx];
    __syncthreads();
#pragma unroll
    for (int i = 0; i < 32; i += 8)
      out[(size_t)(bx + ty + i) * R + by + tx] = f2bf(tile[tx][ty + i]);
  }
}

// ---------------- GEMM main loop: acc += A[bm:bm+BM] * Bt[bn:bn+BN]^T ----------------
// T3 2-phase: double-buffered LDS, stage(k+1) issued BEFORE compute(k); one
// vmcnt(0)+barrier per k-step. 4 waves in 2x2 layout of (BM/2)x(BN/2).
template <int BM, int BN>
__device__ __forceinline__ void gemm_main(const u16* __restrict__ A,
                                          const u16* __restrict__ Bt,
                                          int K, size_t bm, size_t bn,
                                          u16* Al, u16* Bl,
                                          f32x4 (&acc)[BM / 32][BN / 32]) {
  const int tid = threadIdx.x;
  const int lane = tid & 63;
  const int w = tid >> 6;
  const int wr = (w >> 1) * (BM / 2);
  const int wc = (w & 1) * (BN / 2);
  const int srow = lane >> 2;
  const int sch = lane & 3;
  const int kc = lane >> 4;
  const int rl = lane & 15;
  constexpr int ASZ = BM * 32;
  constexpr int BSZ = BN * 32;

  auto stage = [&](int buf, int kt) {
#pragma unroll
    for (int i = 0; i < BM / 64; ++i) {
      int rb = w * 16 + i * 64;
      int row = rb + srow;
      int ch = sch ^ ((row >> 1) & 3);
      gload_lds16(A + (bm + row) * (size_t)K + kt + ch * 8, &Al[buf * ASZ + rb * 32]);
    }
#pragma unroll
    for (int i = 0; i < BN / 64; ++i) {
      int rb = w * 16 + i * 64;
      int row = rb + srow;
      int ch = sch ^ ((row >> 1) & 3);
      gload_lds16(Bt + (bn + row) * (size_t)K + kt + ch * 8, &Bl[buf * BSZ + rb * 32]);
    }
  };

  stage(0, 0);
  asm volatile("s_waitcnt vmcnt(0)" ::: "memory");
  __syncthreads();
  int cur = 0;

  for (int kt = 0; kt < K; kt += 32) {
    if (kt + 32 < K) stage(cur ^ 1, kt + 32);  // prefetch next k-tile

    bf16x8 af[BM / 32], bfr[BN / 32];
#pragma unroll
    for (int m = 0; m < BM / 32; ++m) {
      int row = wr + m * 16 + rl;
      af[m] = ldfrag(&Al[cur * ASZ + row * 32 + (kc ^ ((row >> 1) & 3)) * 8]);
    }
#pragma unroll
    for (int n = 0; n < BN / 32; ++n) {
      int row = wc + n * 16 + rl;
      bfr[n] = ldfrag(&Bl[cur * BSZ + row * 32 + (kc ^ ((row >> 1) & 3)) * 8]);
    }
#pragma unroll
    for (int m = 0; m < BM / 32; ++m)
#pragma unroll
      for (int n = 0; n < BN / 32; ++n)
        acc[m][n] = MFMA16(af[m], bfr[n], acc[m][n]);

    asm volatile("s_waitcnt vmcnt(0)" ::: "memory");  // prefetched tile landed
    __syncthreads();                                  // all waves done reading cur
    cur ^= 1;
  }
}

// single-problem wrapper (WO projection / generic)
template <bool F32OUT, int BM, int BN>
__global__ void gemm_bt(const u16* __restrict__ A, const u16* __restrict__ Bt,
                        void* __restrict__ Cp, int N, int K, float scale) {
  __shared__ u16 Al[2 * BM * 32];
  __shared__ u16 Bl[2 * BN * 32];
  const int lane = threadIdx.x & 63;
  const int w = threadIdx.x >> 6;
  const size_t bm = (size_t)blockIdx.y * BM;
  const size_t bn = (size_t)blockIdx.x * BN;
  f32x4 acc[BM / 32][BN / 32] = {};
  gemm_main<BM, BN>(A, Bt, K, bm, bn, Al, Bl, acc);

  const int wr = (w >> 1) * (BM / 2);
  const int wc = (w & 1) * (BN / 2);
  const int rl = lane & 15;
  const int r0 = (lane >> 4) * 4;
#pragma unroll
  for (int m = 0; m < BM / 32; ++m) {
    size_t grow = bm + wr + m * 16 + r0;
#pragma unroll
    for (int n = 0; n < BN / 32; ++n) {
      size_t gcol = bn + wc + n * 16 + rl;
#pragma unroll
      for (int r = 0; r < 4; ++r) {
        float v = acc[m][n][r] * scale;
        if constexpr (F32OUT)
          ((float*)Cp)[(grow + r) * (size_t)N + gcol] = v;
        else
          ((u16*)Cp)[(grow + r) * (size_t)N + gcol] = f2bf(v);
      }
    }
  }
}

// fused launch: [Q;K] = Acat * qkwT^T (1024 blocks) ++ Vt = vwT * Av^T (512 blocks)
__global__ void gemm_qkv(const u16* __restrict__ Acat, const u16* __restrict__ qkwT,
                         u16* __restrict__ Qb, const u16* __restrict__ vwT,
                         const u16* __restrict__ Av, u16* __restrict__ Vt) {
  __shared__ u16 Al[2 * 128 * 32];
  __shared__ u16 Bl[2 * 128 * 32];
  const int bid = blockIdx.x;
  const int lane = threadIdx.x & 63;
  const int w = threadIdx.x >> 6;
  const u16 *A, *Bt;
  u16* C;
  size_t bm, bn;
  int N;
  if (bid < 1024) {
    A = Acat; Bt = qkwT; C = Qb; N = 2048;
    bm = (size_t)(bid >> 4) * 128;
    bn = (size_t)(bid & 15) * 128;
  } else {
    A = vwT; Bt = Av; C = Vt; N = 4096;
    bm = (size_t)((bid - 1024) >> 5) * 128;
    bn = (size_t)((bid - 1024) & 31) * 128;
  }
  f32x4 acc[4][4] = {};
  gemm_main<128, 128>(A, Bt, 512, bm, bn, Al, Bl, acc);

  const int wr = (w >> 1) * 64;
  const int wc = (w & 1) * 64;
  const int rl = lane & 15;
  const int r0 = (lane >> 4) * 4;
#pragma unroll
  for (int m = 0; m < 4; ++m) {
    size_t grow = bm + wr + m * 16 + r0;
#pragma unroll
    for (int n = 0; n < 4; ++n) {
      size_t gcol = bn + wc + n * 16 + rl;
#pragma unroll
      for (int r = 0; r < 4; ++r)
        C[(grow + r) * (size_t)N + gcol] = f2bf(acc[m][n][r]);
    }
  }
}

// ---- gated GEMM: acc = x_bf * [qkr;vr]^T fused with gate multiply ----
__global__ void gemm_gate(const u16* __restrict__ A, const u16* __restrict__ Bt,
                          const float* __restrict__ gq, const float* __restrict__ gk,
                          const float* __restrict__ gv, u16* __restrict__ Aq,
                          u16* __restrict__ Ak, u16* __restrict__ Av, int K) {
  __shared__ u16 Al[2 * 128 * 32];
  __shared__ u16 Bl[2 * 64 * 32];
  const float SC = 0.1275255128608411f;  // 1/sqrt(128) * log2(e)
  const int lane = threadIdx.x & 63;
  const int w = threadIdx.x >> 6;
  const size_t bm = (size_t)blockIdx.y * 128;
  const size_t bn = (size_t)blockIdx.x * 64;
  f32x4 acc[4][2] = {};
  gemm_main<128, 64>(A, Bt, K, bm, bn, Al, Bl, acc);

  const int wr = (w >> 1) * 64;
  const int wc = (w & 1) * 32;
  const int rl = lane & 15;
  const int r0 = (lane >> 4) * 4;
  const bool phalf = (bn < 512);  // uniform per block
#pragma unroll
  for (int m = 0; m < 4; ++m) {
    size_t grow = bm + wr + m * 16 + r0;
#pragma unroll
    for (int n = 0; n < 2; ++n) {
      size_t gcol = bn + wc + n * 16 + rl;
#pragma unroll
      for (int r = 0; r < 4; ++r) {
        float v = acc[m][n][r];
        if (phalf) {
          size_t idx = (grow + r) * 512 + gcol;
          Aq[idx] = f2bf(gq[idx] * SC * v);
          Ak[idx] = f2bf(gk[idx] * v);
        } else {
          size_t idx = (grow + r) * 512 + (gcol - 512);
          Av[idx] = f2bf(gv[idx] * v);
        }
      }
    }
  }
}

// ---------------- flash attention (causal, 16 heads, d_head=128) ----------------
// R9 base + 3-buffer K pipeline: end-of-iter barrier is RAW (no vmcnt drain);
// K_{t+2} stays in flight across it. Mid vmcnt(4) lands {K_{t+1}, V_t}.
// LDS 64KB (Kl 3x16K + Vl 16K) -> same 2 blocks/CU as 48KB config.
// grid x = bh (32) -> T1 XCD locality; y: qb = 31-y (heavy first).
// 4 waves x 16 q-rows; swapped QK^T (T12) in-register softmax; P aliased
// into Kl[cur] (wave-private region, dead after QK).
__global__ __launch_bounds__(256, 2) void attn_kernel(const u16* __restrict__ Q,
                                                      const u16* __restrict__ Kg,
                                                      const u16* __restrict__ Vt,
                                                      u16* __restrict__ AO) {
  __shared__ u16 Kl[3][64 * 128];  // 48 KB; P (2KB/wave) aliases into Kl[cur]
  __shared__ u16 Vl[128 * 64];     // 16 KB

  const int tid = threadIdx.x;
  const int lane = tid & 63;
  const int w = tid >> 6;
  const int bh = blockIdx.x;
  const int qb = 31 - blockIdx.y;  // heavy q-tiles dispatched first
  const int b = bh >> 4;
  const int h = bh & 15;

  const int rl = lane & 15;
  const int g4 = lane >> 4;

  const float THR = 10.0f;  // defer-rescale threshold (log2 units)

  bf16x8 ones;
  {
    u16x8 ou;
#pragma unroll
    for (int j = 0; j < 8; ++j) ou[j] = 0x3F80;  // bf16 1.0
    ones = __builtin_bit_cast(bf16x8, ou);
  }

  auto stageK = [&](int buf, int t0) {
    int roff = lane >> 4;
    int cch = lane & 15;
#pragma unroll
    for (int i = 0; i < 4; ++i) {
      int rb = w * 16 + i * 4;
      int row = rb + roff;
      int ch = cch ^ (row & 7);
      gload_lds16(Kg + ((size_t)b * 2048 + t0 + row) * 2048 + h * 128 + ch * 8,
                  &Kl[buf][rb * 128]);
    }
  };
  auto stageV = [&](int t0) {
    int roff = lane >> 3;
    int cch = lane & 7;
#pragma unroll
    for (int i = 0; i < 4; ++i) {
      int rb = w * 32 + i * 8;
      int row = rb + roff;
      int ch = cch ^ (row & 7);
      gload_lds16(Vt + (size_t)(h * 128 + row) * 4096 + (size_t)b * 2048 + t0 + ch * 8,
                  &Vl[rb * 64]);
    }
  };

  const int ntiles = qb + 1;
  const int qq = qb * 64 + w * 16 + rl;  // this lane's q row (within b)
  const size_t qrow0 = (size_t)b * 2048 + (size_t)qb * 64;

  bf16x8 qf[4];
  {
    const u16* qp = Q + (qrow0 + w * 16 + rl) * 2048 + h * 128 + g4 * 8;
#pragma unroll
    for (int ks = 0; ks < 4; ++ks) qf[ks] = ldfrag(qp + ks * 32);
  }

  float m_r = -3.0e38f;  // running max for q row = qq (per lane)
  float l_r[4];          // denominator in MFMA-row layout (rows g4*4+r)
#pragma unroll
  for (int r = 0; r < 4; ++r) l_r[r] = 0.f;
  f32x4 oacc[8] = {};

  // prologue: K_0 (and K_1 when present); wait lands K_0, leaves K_1 flying
  stageK(0, 0);
  if (ntiles > 1) {
    stageK(1, 64);
    asm volatile("s_waitcnt vmcnt(4)\n\ts_barrier" ::: "memory");
  } else {
    asm volatile("s_waitcnt vmcnt(0)\n\ts_barrier" ::: "memory");
  }
  int cur = 0;

#pragma unroll 1
  for (int t = 0; t < ntiles; ++t) {
    const int t0 = t * 64;
    stageV(t0);  // V for THIS tile
    const bool pref2 = (t + 2 < ntiles);
    if (pref2) {
      int nxt2 = cur + 2;
      if (nxt2 >= 3) nxt2 -= 3;
      stageK(nxt2, (t + 2) * 64);  // K two tiles ahead
    }

    // ---- QK^T, swapped: c = mfma(K, Q) -> P[t = nf*16+g4*4+r][q = rl] ----
    // Kl[cur] landed: prologue (t=0) or prior iter's mid barrier (t>0).
    float p[4][4];
    __builtin_amdgcn_s_setprio(1);
#pragma unroll
    for (int nf = 0; nf < 4; ++nf) {
      f32x4 c = {};
      int trow = nf * 16 + rl;
#pragma unroll
      for (int ks = 0; ks < 4; ++ks) {
        bf16x8 kf = ldfrag(&Kl[cur][trow * 128 + ((ks * 4 + g4) ^ (trow & 7)) * 8]);
        c = MFMA16(kf, qf[ks], c);
      }
      if (t == qb) {  // diagonal tile: causal mask (t_global <= qq)
        int tb = t0 + nf * 16 + g4 * 4;
#pragma unroll
        for (int r = 0; r < 4; ++r)
          p[nf][r] = (tb + r <= qq) ? c[r] : -3.0e38f;
      } else {
#pragma unroll
        for (int r = 0; r < 4; ++r) p[nf][r] = c[r];
      }
    }
    __builtin_amdgcn_s_setprio(0);

    // row max: 15 in-lane fmax + 2 shfl_xor across g4 groups
    float mx = p[0][0];
#pragma unroll
    for (int nf = 0; nf < 4; ++nf)
#pragma unroll
      for (int r = 0; r < 4; ++r) mx = fmaxf(mx, p[nf][r]);
    mx = fmaxf(mx, __shfl_xor(mx, 16));
    mx = fmaxf(mx, __shfl_xor(mx, 32));

    // T13 defer-rescale (scalar m per lane; alpha pulled to row layout on trigger)
    if (__any(mx - m_r > THR)) {
      float mn = fmaxf(m_r, mx);
      float alpha = exp2f(m_r - mn);
      m_r = mn;
#pragma unroll
      for (int r = 0; r < 4; ++r) {
        float av = __shfl(alpha, g4 * 4 + r, 16);
        l_r[r] *= av;
#pragma unroll
        for (int nf = 0; nf < 8; ++nf) oacc[nf][r] *= av;
      }
    }

    // exp + pack pairs (trunc) -> 2 u32 per nf (register-only, before barrier)
    u32x2 pk[4];
#pragma unroll
    for (int nf = 0; nf < 4; ++nf) {
      u32 e0 = __builtin_bit_cast(u32, exp2f(p[nf][0] - m_r));
      u32 e1 = __builtin_bit_cast(u32, exp2f(p[nf][1] - m_r));
      u32 e2 = __builtin_bit_cast(u32, exp2f(p[nf][2] - m_r));
      u32 e3 = __builtin_bit_cast(u32, exp2f(p[nf][3] - m_r));
      pk[nf][0] = (e1 & 0xffff0000u) | (e0 >> 16);
      pk[nf][1] = (e3 & 0xffff0000u) | (e2 >> 16);
    }

    // Mid barrier: land {K_{t+1}, V_t} (oldest 8 of 12), keep K_{t+2} flying.
    // All waves waited own V_t + K_{t+1} -> after barrier both fully landed.
    if (pref2) asm volatile("s_waitcnt vmcnt(4)\n\ts_barrier" ::: "memory");
    else       asm volatile("s_waitcnt vmcnt(0)\n\ts_barrier" ::: "memory");

    // P -> LDS: 4 x ds_write_b64, swizzled; aliased into Kl[cur] (dead tile,
    // wave-private 1KB region)
    u16* pl = &Kl[cur][w * 1024];
#pragma unroll
    for (int nf = 0; nf < 4; ++nf) {
      int c8 = ((nf * 2 + (g4 >> 1)) ^ (rl & 7)) * 8 + (g4 & 1) * 4;
      *(u32x2*)(&pl[rl * 64 + c8]) = pk[nf];
    }

    // ---- PV (+ rsum via MFMA with ones) ----
    __builtin_amdgcn_s_setprio(1);
    f32x4 rs = {};
#pragma unroll
    for (int ks = 0; ks < 2; ++ks) {
      bf16x8 pa = ldfrag(&pl[rl * 64 + ((ks * 4 + g4) ^ (rl & 7)) * 8]);
#pragma unroll
      for (int nf = 0; nf < 8; ++nf) {
        int drow = nf * 16 + rl;
        bf16x8 vf = ldfrag(&Vl[drow * 64 + ((ks * 4 + g4) ^ (drow & 7)) * 8]);
        oacc[nf] = MFMA16(pa, vf, oacc[nf]);
      }
      rs = MFMA16(pa, ones, rs);
    }
    __builtin_amdgcn_s_setprio(0);
#pragma unroll
    for (int r = 0; r < 4; ++r) l_r[r] += rs[r];

    // End barrier: RAW -- K_{t+2} stays in flight. Orders Vl/P reuse only
    // (all waves' PV reads completed; next stageV/stageK issue after).
    asm volatile("s_barrier" ::: "memory");
    cur = (cur == 2) ? 0 : cur + 1;
  }

  // epilogue (oacc and l_r share the MFMA-row layout)
#pragma unroll
  for (int nf = 0; nf < 8; ++nf) {
    size_t dc = (size_t)h * 128 + nf * 16 + rl;
#pragma unroll
    for (int r = 0; r < 4; ++r) {
      float v = oacc[nf][r] / l_r[r];
      AO[(qrow0 + w * 16 + g4 * 4 + r) * 2048 + dc] = f2bf(v);
    }
  }
}

// ---------------- launch ----------------

extern "C" void kernel_launch(void* const* d_in, const int* in_sizes, int n_in,
                              void* d_out, int out_size, void* d_ws, size_t ws_size,
                              hipStream_t stream) {
  const float* x = (const float*)d_in[0];
  const float* gQ = (const float*)d_in[1];
  const float* gK = (const float*)d_in[2];
  const float* gV = (const float*)d_in[3];
  const float* qkr = (const float*)d_in[4];
  const float* qkw = (const float*)d_in[5];
  const float* vr = (const float*)d_in[6];
  const float* vw = (const float*)d_in[7];
  const float* wo = (const float*)d_in[8];
  float* out = (float*)d_out;

  u16* p = (u16*)d_ws;
  u16* x_bf = p;   p += 8388608;   // [4096][2048]; later reused as Vt [2048][4096]
  u16* qkr_b = p;  p += 1048576;   // [512][2048]  \ adjacent -> Bt_cat [1024][2048]
  u16* vr_b = p;   p += 1048576;   // [512][2048]  /
  u16* qkwT = p;   p += 1048576;   // [2048][512]
  u16* vwT = p;    p += 1048576;   // [2048][512]
  u16* woT = p;    p += 4194304;   // [2048][2048]
  u16* Aq = p;     p += 2097152;   // [4096][512]  \ adjacent -> A_cat [8192][512]
  u16* Ak = p;     p += 2097152;   // [4096][512]  /
  u16* Av = p;     p += 2097152;   // [4096][512]
  u16* Qb = p;     p += 8388608;   // [4096][2048] \ adjacent -> C_cat [8192][2048]
  u16* Kb = p;     p += 8388608;   // [4096][2048] /
  u16* Vt = x_bf;                  // alias: x_bf dead after gemm_gate
  u16* AO = Qb;                    // alias: block writes exactly the Q region it read

  // all input converts/transposes in ONE launch (mutually independent)
  prep_kernel<<<16384, 256, 0, stream>>>(x, qkr, vr, qkw, vw, wo,
                                         x_bf, qkr_b, vr_b, qkwT, vwT, woT);

  // gated low-rank projections: Aq/Ak/Av = gate(x_bf * [qkr;vr]^T)  (K=2048)
  gemm_gate<<<dim3(16, 32), 256, 0, stream>>>(x_bf, qkr_b, gQ, gK, gV, Aq, Ak, Av, 2048);

  // [Q;K] = Acat * qk_write (M=8192,N=2048,K=512)  ++  Vt = vwT * Av^T (M=2048,N=4096)
  gemm_qkv<<<1536, 256, 0, stream>>>(Aq, qkwT, Qb, vwT, Av, Vt);

  // attention -> AO (bf16, [4096][2048])
  attn_kernel<<<dim3(32, 32), 256, 0, stream>>>(Qb, Kb, Vt, AO);

  // out = AO * W_O * 1/keep^2   (f32 out)
  gemm_bt<true, 128, 128><<<dim3(16, 32), 256, 0, stream>>>(AO, woT, out, 2048, 2048,
                                                            1.2345679012345678f);
}

// Round 16
// 209.748 us; speedup vs baseline: 1.0204x; 1.0204x over previous
//
#include <hip/hip_runtime.h>
#include <cstdint>
#include <cstddef>

typedef unsigned short u16;
typedef unsigned int u32;
typedef __attribute__((ext_vector_type(4))) float f32x4;
typedef __attribute__((ext_vector_type(8))) __bf16 bf16x8;
typedef __attribute__((ext_vector_type(8))) u16 u16x8;
typedef __attribute__((ext_vector_type(4))) u16 u16x4;
typedef __attribute__((ext_vector_type(2))) u32 u32x2;

__device__ __forceinline__ u16 f2bf(float x) {
  u32 u = __builtin_bit_cast(u32, x);
  u += 0x7fffu + ((u >> 16) & 1u);
  return (u16)(u >> 16);
}
__device__ __forceinline__ float bf2f(u16 b) {
  return __builtin_bit_cast(float, (u32)b << 16);
}
__device__ __forceinline__ bf16x8 ldfrag(const u16* p) {
  return __builtin_bit_cast(bf16x8, *(const u16x8*)p);
}
__device__ __forceinline__ void gload_lds16(const void* g, void* l) {
  auto gp = (const __attribute__((address_space(1))) u32*)g;
  auto lp = (__attribute__((address_space(3))) u32*)l;
  __builtin_amdgcn_global_load_lds(gp, lp, 16, 0, 0);
}
#define MFMA16(a, b, c) __builtin_amdgcn_mfma_f32_16x16x32_bf16(a, b, c, 0, 0, 0)

// ---------------- fused prep: 3 bf16 converts + 3 transposed converts ----------------
__global__ void prep_kernel(const float* __restrict__ x, const float* __restrict__ qkr,
                            const float* __restrict__ vr, const float* __restrict__ qkw,
                            const float* __restrict__ vw, const float* __restrict__ wo,
                            u16* __restrict__ x_bf, u16* __restrict__ qkr_b,
                            u16* __restrict__ vr_b, u16* __restrict__ qkwT,
                            u16* __restrict__ vwT, u16* __restrict__ woT) {
  __shared__ float tile[32][33];
  const int bid = blockIdx.x;
  const int tid = threadIdx.x;
  if (bid < 10240) {  // element-wise f32 -> bf16
    const float* in;
    u16* out;
    int base;
    if (bid < 8192) { in = x; out = x_bf; base = bid; }
    else if (bid < 9216) { in = qkr; out = qkr_b; base = bid - 8192; }
    else { in = vr; out = vr_b; base = bid - 9216; }
    int i = base * 1024 + tid * 4;
    f32x4 v = *(const f32x4*)(in + i);
    u16x4 r = { f2bf(v[0]), f2bf(v[1]), f2bf(v[2]), f2bf(v[3]) };
    *(u16x4*)(out + i) = r;
  } else {  // 32x32 tiled transpose + bf16
    const float* in;
    u16* out;
    int R, C, local;
    if (bid < 11264) { in = qkw; out = qkwT; R = 512; C = 2048; local = bid - 10240; }
    else if (bid < 12288) { in = vw; out = vwT; R = 512; C = 2048; local = bid - 11264; }
    else { in = wo; out = woT; R = 2048; C = 2048; local = bid - 12288; }
    int bx = (local & 63) * 32, by = (local >> 6) * 32;
    int tx = tid & 31, ty = tid >> 5;
#pragma unroll
    for (int i = 0; i < 32; i += 8)
      tile[ty + i][tx] = in[(size_t)(by + ty + i) * C + bx + tx];
    __syncthreads();
#pragma unroll
    for (int i = 0; i < 32; i += 8)
      out[(size_t)(bx + ty + i) * R + by + tx] = f2bf(tile[tx][ty + i]);
  }
}

// ---------------- GEMM main loop: acc += A[bm:bm+BM] * Bt[bn:bn+BN]^T ----------------
// T3 2-phase: double-buffered LDS, stage(k+1) issued BEFORE compute(k); one
// vmcnt(0)+barrier per k-step -> HBM flight overlaps ds_read+MFMA.
// 4 waves in 2x2 layout of (BM/2)x(BN/2).
template <int BM, int BN>
__device__ __forceinline__ void gemm_main(const u16* __restrict__ A,
                                          const u16* __restrict__ Bt,
                                          int K, size_t bm, size_t bn,
                                          u16* Al, u16* Bl,
                                          f32x4 (&acc)[BM / 32][BN / 32]) {
  const int tid = threadIdx.x;
  const int lane = tid & 63;
  const int w = tid >> 6;
  const int wr = (w >> 1) * (BM / 2);
  const int wc = (w & 1) * (BN / 2);
  const int srow = lane >> 2;
  const int sch = lane & 3;
  const int kc = lane >> 4;
  const int rl = lane & 15;
  constexpr int ASZ = BM * 32;
  constexpr int BSZ = BN * 32;

  auto stage = [&](int buf, int kt) {
#pragma unroll
    for (int i = 0; i < BM / 64; ++i) {
      int rb = w * 16 + i * 64;
      int row = rb + srow;
      int ch = sch ^ ((row >> 1) & 3);
      gload_lds16(A + (bm + row) * (size_t)K + kt + ch * 8, &Al[buf * ASZ + rb * 32]);
    }
#pragma unroll
    for (int i = 0; i < BN / 64; ++i) {
      int rb = w * 16 + i * 64;
      int row = rb + srow;
      int ch = sch ^ ((row >> 1) & 3);
      gload_lds16(Bt + (bn + row) * (size_t)K + kt + ch * 8, &Bl[buf * BSZ + rb * 32]);
    }
  };

  stage(0, 0);
  asm volatile("s_waitcnt vmcnt(0)" ::: "memory");
  __syncthreads();
  int cur = 0;

  for (int kt = 0; kt < K; kt += 32) {
    if (kt + 32 < K) stage(cur ^ 1, kt + 32);  // prefetch next k-tile

    bf16x8 af[BM / 32], bfr[BN / 32];
#pragma unroll
    for (int m = 0; m < BM / 32; ++m) {
      int row = wr + m * 16 + rl;
      af[m] = ldfrag(&Al[cur * ASZ + row * 32 + (kc ^ ((row >> 1) & 3)) * 8]);
    }
#pragma unroll
    for (int n = 0; n < BN / 32; ++n) {
      int row = wc + n * 16 + rl;
      bfr[n] = ldfrag(&Bl[cur * BSZ + row * 32 + (kc ^ ((row >> 1) & 3)) * 8]);
    }
#pragma unroll
    for (int m = 0; m < BM / 32; ++m)
#pragma unroll
      for (int n = 0; n < BN / 32; ++n)
        acc[m][n] = MFMA16(af[m], bfr[n], acc[m][n]);

    asm volatile("s_waitcnt vmcnt(0)" ::: "memory");  // prefetched tile landed
    __syncthreads();                                  // all waves done reading cur
    cur ^= 1;
  }
}

// single-problem wrapper (WO projection / generic)
template <bool F32OUT, int BM, int BN>
__global__ void gemm_bt(const u16* __restrict__ A, const u16* __restrict__ Bt,
                        void* __restrict__ Cp, int N, int K, float scale) {
  __shared__ u16 Al[2 * BM * 32];
  __shared__ u16 Bl[2 * BN * 32];
  const int lane = threadIdx.x & 63;
  const int w = threadIdx.x >> 6;
  const size_t bm = (size_t)blockIdx.y * BM;
  const size_t bn = (size_t)blockIdx.x * BN;
  f32x4 acc[BM / 32][BN / 32] = {};
  gemm_main<BM, BN>(A, Bt, K, bm, bn, Al, Bl, acc);

  const int wr = (w >> 1) * (BM / 2);
  const int wc = (w & 1) * (BN / 2);
  const int rl = lane & 15;
  const int r0 = (lane >> 4) * 4;
#pragma unroll
  for (int m = 0; m < BM / 32; ++m) {
    size_t grow = bm + wr + m * 16 + r0;
#pragma unroll
    for (int n = 0; n < BN / 32; ++n) {
      size_t gcol = bn + wc + n * 16 + rl;
#pragma unroll
      for (int r = 0; r < 4; ++r) {
        float v = acc[m][n][r] * scale;
        if constexpr (F32OUT)
          ((float*)Cp)[(grow + r) * (size_t)N + gcol] = v;
        else
          ((u16*)Cp)[(grow + r) * (size_t)N + gcol] = f2bf(v);
      }
    }
  }
}

// fused launch: [Q;K] = Acat * qkwT^T (1024 blocks) ++ Vt = vwT * Av^T (512 blocks)
__global__ void gemm_qkv(const u16* __restrict__ Acat, const u16* __restrict__ qkwT,
                         u16* __restrict__ Qb, const u16* __restrict__ vwT,
                         const u16* __restrict__ Av, u16* __restrict__ Vt) {
  __shared__ u16 Al[2 * 128 * 32];
  __shared__ u16 Bl[2 * 128 * 32];
  const int bid = blockIdx.x;
  const int lane = threadIdx.x & 63;
  const int w = threadIdx.x >> 6;
  const u16 *A, *Bt;
  u16* C;
  size_t bm, bn;
  int N;
  if (bid < 1024) {
    A = Acat; Bt = qkwT; C = Qb; N = 2048;
    bm = (size_t)(bid >> 4) * 128;
    bn = (size_t)(bid & 15) * 128;
  } else {
    A = vwT; Bt = Av; C = Vt; N = 4096;
    bm = (size_t)((bid - 1024) >> 5) * 128;
    bn = (size_t)((bid - 1024) & 31) * 128;
  }
  f32x4 acc[4][4] = {};
  gemm_main<128, 128>(A, Bt, 512, bm, bn, Al, Bl, acc);

  const int wr = (w >> 1) * 64;
  const int wc = (w & 1) * 64;
  const int rl = lane & 15;
  const int r0 = (lane >> 4) * 4;
#pragma unroll
  for (int m = 0; m < 4; ++m) {
    size_t grow = bm + wr + m * 16 + r0;
#pragma unroll
    for (int n = 0; n < 4; ++n) {
      size_t gcol = bn + wc + n * 16 + rl;
#pragma unroll
      for (int r = 0; r < 4; ++r)
        C[(grow + r) * (size_t)N + gcol] = f2bf(acc[m][n][r]);
    }
  }
}

// ---- gated GEMM: acc = x_bf * [qkr;vr]^T fused with gate multiply ----
// BM=128, BN=64 -> 512 blocks (2/CU supply). cols<512: Aq = gq*SC*acc,
// Ak = gk*acc ; cols>=512: Av = gv*acc (all bf16)
__global__ void gemm_gate(const u16* __restrict__ A, const u16* __restrict__ Bt,
                          const float* __restrict__ gq, const float* __restrict__ gk,
                          const float* __restrict__ gv, u16* __restrict__ Aq,
                          u16* __restrict__ Ak, u16* __restrict__ Av, int K) {
  __shared__ u16 Al[2 * 128 * 32];
  __shared__ u16 Bl[2 * 64 * 32];
  const float SC = 0.1275255128608411f;  // 1/sqrt(128) * log2(e)
  const int lane = threadIdx.x & 63;
  const int w = threadIdx.x >> 6;
  const size_t bm = (size_t)blockIdx.y * 128;
  const size_t bn = (size_t)blockIdx.x * 64;
  f32x4 acc[4][2] = {};
  gemm_main<128, 64>(A, Bt, K, bm, bn, Al, Bl, acc);

  const int wr = (w >> 1) * 64;
  const int wc = (w & 1) * 32;
  const int rl = lane & 15;
  const int r0 = (lane >> 4) * 4;
  const bool phalf = (bn < 512);  // uniform per block
#pragma unroll
  for (int m = 0; m < 4; ++m) {
    size_t grow = bm + wr + m * 16 + r0;
#pragma unroll
    for (int n = 0; n < 2; ++n) {
      size_t gcol = bn + wc + n * 16 + rl;
#pragma unroll
      for (int r = 0; r < 4; ++r) {
        float v = acc[m][n][r];
        if (phalf) {
          size_t idx = (grow + r) * 512 + gcol;
          Aq[idx] = f2bf(gq[idx] * SC * v);
          Ak[idx] = f2bf(gk[idx] * v);
        } else {
          size_t idx = (grow + r) * 512 + (gcol - 512);
          Av[idx] = f2bf(gv[idx] * v);
        }
      }
    }
  }
}

// ---------------- flash attention (causal, 16 heads, d_head=128) ----------------
// R9-exact (proven ~75us; FROZEN). grid x = bh (32) -> T1 XCD locality;
// y: qb = 31-y (heavy first). 4 waves x 16 q-rows. K dbuf 32K + V single 16K;
// P aliased into Kl[cur]. Swapped QK^T (T12) in-register softmax; counted
// vmcnt(4) keeps K prefetch in flight across the raw mid s_barrier.
__global__ __launch_bounds__(256, 3) void attn_kernel(const u16* __restrict__ Q,
                                                      const u16* __restrict__ Kg,
                                                      const u16* __restrict__ Vt,
                                                      u16* __restrict__ AO) {
  __shared__ u16 Kl[2][64 * 128];  // 32 KB; P (2KB/wave) aliases into Kl[cur]
  __shared__ u16 Vl[128 * 64];     // 16 KB

  const int tid = threadIdx.x;
  const int lane = tid & 63;
  const int w = tid >> 6;
  const int bh = blockIdx.x;
  const int qb = 31 - blockIdx.y;  // heavy q-tiles dispatched first
  const int b = bh >> 4;
  const int h = bh & 15;

  const int rl = lane & 15;
  const int g4 = lane >> 4;

  const float THR = 10.0f;  // defer-rescale threshold (log2 units)

  bf16x8 ones;
  {
    u16x8 ou;
#pragma unroll
    for (int j = 0; j < 8; ++j) ou[j] = 0x3F80;  // bf16 1.0
    ones = __builtin_bit_cast(bf16x8, ou);
  }

  auto stageK = [&](int buf, int t0) {
    int roff = lane >> 4;
    int cch = lane & 15;
#pragma unroll
    for (int i = 0; i < 4; ++i) {
      int rb = w * 16 + i * 4;
      int row = rb + roff;
      int ch = cch ^ (row & 7);
      gload_lds16(Kg + ((size_t)b * 2048 + t0 + row) * 2048 + h * 128 + ch * 8,
                  &Kl[buf][rb * 128]);
    }
  };
  auto stageV = [&](int t0) {
    int roff = lane >> 3;
    int cch = lane & 7;
#pragma unroll
    for (int i = 0; i < 4; ++i) {
      int rb = w * 32 + i * 8;
      int row = rb + roff;
      int ch = cch ^ (row & 7);
      gload_lds16(Vt + (size_t)(h * 128 + row) * 4096 + (size_t)b * 2048 + t0 + ch * 8,
                  &Vl[rb * 64]);
    }
  };

  const int ntiles = qb + 1;
  const int qq = qb * 64 + w * 16 + rl;  // this lane's q row (within b)
  const size_t qrow0 = (size_t)b * 2048 + (size_t)qb * 64;

  bf16x8 qf[4];
  {
    const u16* qp = Q + (qrow0 + w * 16 + rl) * 2048 + h * 128 + g4 * 8;
#pragma unroll
    for (int ks = 0; ks < 4; ++ks) qf[ks] = ldfrag(qp + ks * 32);
  }

  float m_r = -3.0e38f;  // running max for q row = qq (per lane)
  float l_r[4];          // denominator in MFMA-row layout (rows g4*4+r)
#pragma unroll
  for (int r = 0; r < 4; ++r) l_r[r] = 0.f;
  f32x4 oacc[8] = {};

  stageK(0, 0);
  __syncthreads();
  int cur = 0;

#pragma unroll 1
  for (int t = 0; t < ntiles; ++t) {
    const int t0 = t * 64;
    stageV(t0);  // V for THIS tile (issued first; drained by vmcnt(4) below)
    const bool pref = (t + 1 < ntiles);
    if (pref) stageK(cur ^ 1, (t + 1) * 64);

    // ---- QK^T, swapped: c = mfma(K, Q) -> P[t = nf*16+g4*4+r][q = rl] ----
    float p[4][4];
    __builtin_amdgcn_s_setprio(1);
#pragma unroll
    for (int nf = 0; nf < 4; ++nf) {
      f32x4 c = {};
      int trow = nf * 16 + rl;
#pragma unroll
      for (int ks = 0; ks < 4; ++ks) {
        bf16x8 kf = ldfrag(&Kl[cur][trow * 128 + ((ks * 4 + g4) ^ (trow & 7)) * 8]);
        c = MFMA16(kf, qf[ks], c);
      }
      if (t == qb) {  // diagonal tile: causal mask (t_global <= qq)
        int tb = t0 + nf * 16 + g4 * 4;
#pragma unroll
        for (int r = 0; r < 4; ++r)
          p[nf][r] = (tb + r <= qq) ? c[r] : -3.0e38f;
      } else {
#pragma unroll
        for (int r = 0; r < 4; ++r) p[nf][r] = c[r];
      }
    }
    __builtin_amdgcn_s_setprio(0);

    // row max: 15 in-lane fmax + 2 shfl_xor across g4 groups
    float mx = p[0][0];
#pragma unroll
    for (int nf = 0; nf < 4; ++nf)
#pragma unroll
      for (int r = 0; r < 4; ++r) mx = fmaxf(mx, p[nf][r]);
    mx = fmaxf(mx, __shfl_xor(mx, 16));
    mx = fmaxf(mx, __shfl_xor(mx, 32));

    // T13 defer-rescale (scalar m per lane; alpha pulled to row layout on trigger)
    if (__any(mx - m_r > THR)) {
      float mn = fmaxf(m_r, mx);
      float alpha = exp2f(m_r - mn);
      m_r = mn;
#pragma unroll
      for (int r = 0; r < 4; ++r) {
        float av = __shfl(alpha, g4 * 4 + r, 16);
        l_r[r] *= av;
#pragma unroll
        for (int nf = 0; nf < 8; ++nf) oacc[nf][r] *= av;
      }
    }

    // exp + pack pairs (trunc) -> 2 u32 per nf (register-only, before barrier)
    u32x2 pk[4];
#pragma unroll
    for (int nf = 0; nf < 4; ++nf) {
      u32 e0 = __builtin_bit_cast(u32, exp2f(p[nf][0] - m_r));
      u32 e1 = __builtin_bit_cast(u32, exp2f(p[nf][1] - m_r));
      u32 e2 = __builtin_bit_cast(u32, exp2f(p[nf][2] - m_r));
      u32 e3 = __builtin_bit_cast(u32, exp2f(p[nf][3] - m_r));
      pk[nf][0] = (e1 & 0xffff0000u) | (e0 >> 16);
      pk[nf][1] = (e3 & 0xffff0000u) | (e2 >> 16);
    }

    // Drain own V loads (K prefetch stays in flight), then join waves.
    if (pref) asm volatile("s_waitcnt vmcnt(4)\n\ts_barrier" ::: "memory");
    else      asm volatile("s_waitcnt vmcnt(0)\n\ts_barrier" ::: "memory");

    // P -> LDS: 4 x ds_write_b64, swizzled; aliased into Kl[cur] (dead tile)
    u16* pl = &Kl[cur][w * 1024];
#pragma unroll
    for (int nf = 0; nf < 4; ++nf) {
      int c8 = ((nf * 2 + (g4 >> 1)) ^ (rl & 7)) * 8 + (g4 & 1) * 4;
      *(u32x2*)(&pl[rl * 64 + c8]) = pk[nf];
    }

    // ---- PV (+ rsum via MFMA with ones) ----
    __builtin_amdgcn_s_setprio(1);
    f32x4 rs = {};
#pragma unroll
    for (int ks = 0; ks < 2; ++ks) {
      bf16x8 pa = ldfrag(&pl[rl * 64 + ((ks * 4 + g4) ^ (rl & 7)) * 8]);
#pragma unroll
      for (int nf = 0; nf < 8; ++nf) {
        int drow = nf * 16 + rl;
        bf16x8 vf = ldfrag(&Vl[drow * 64 + ((ks * 4 + g4) ^ (drow & 7)) * 8]);
        oacc[nf] = MFMA16(pa, vf, oacc[nf]);
      }
      rs = MFMA16(pa, ones, rs);
    }
    __builtin_amdgcn_s_setprio(0);
#pragma unroll
    for (int r = 0; r < 4; ++r) l_r[r] += rs[r];

    __syncthreads();  // all waves done with Vl/pl; drains K prefetch
    cur ^= 1;
  }

  // epilogue (oacc and l_r share the MFMA-row layout)
#pragma unroll
  for (int nf = 0; nf < 8; ++nf) {
    size_t dc = (size_t)h * 128 + nf * 16 + rl;
#pragma unroll
    for (int r = 0; r < 4; ++r) {
      float v = oacc[nf][r] / l_r[r];
      AO[(qrow0 + w * 16 + g4 * 4 + r) * 2048 + dc] = f2bf(v);
    }
  }
}

// ---------------- launch ----------------

extern "C" void kernel_launch(void* const* d_in, const int* in_sizes, int n_in,
                              void* d_out, int out_size, void* d_ws, size_t ws_size,
                              hipStream_t stream) {
  const float* x = (const float*)d_in[0];
  const float* gQ = (const float*)d_in[1];
  const float* gK = (const float*)d_in[2];
  const float* gV = (const float*)d_in[3];
  const float* qkr = (const float*)d_in[4];
  const float* qkw = (const float*)d_in[5];
  const float* vr = (const float*)d_in[6];
  const float* vw = (const float*)d_in[7];
  const float* wo = (const float*)d_in[8];
  float* out = (float*)d_out;

  u16* p = (u16*)d_ws;
  u16* x_bf = p;   p += 8388608;   // [4096][2048]; later reused as Vt [2048][4096]
  u16* qkr_b = p;  p += 1048576;   // [512][2048]  \ adjacent -> Bt_cat [1024][2048]
  u16* vr_b = p;   p += 1048576;   // [512][2048]  /
  u16* qkwT = p;   p += 1048576;   // [2048][512]
  u16* vwT = p;    p += 1048576;   // [2048][512]
  u16* woT = p;    p += 4194304;   // [2048][2048]
  u16* Aq = p;     p += 2097152;   // [4096][512]  \ adjacent -> A_cat [8192][512]
  u16* Ak = p;     p += 2097152;   // [4096][512]  /
  u16* Av = p;     p += 2097152;   // [4096][512]
  u16* Qb = p;     p += 8388608;   // [4096][2048] \ adjacent -> C_cat [8192][2048]
  u16* Kb = p;     p += 8388608;   // [4096][2048] /
  u16* Vt = x_bf;                  // alias: x_bf dead after gemm_gate
  u16* AO = Qb;                    // alias: block writes exactly the Q region it read

  // all input converts/transposes in ONE launch (mutually independent)
  prep_kernel<<<16384, 256, 0, stream>>>(x, qkr, vr, qkw, vw, wo,
                                         x_bf, qkr_b, vr_b, qkwT, vwT, woT);

  // gated low-rank projections: Aq/Ak/Av = gate(x_bf * [qkr;vr]^T)  (K=2048)
  // BM=128 BN=64 -> 512 blocks (2/CU) + 2-phase prefetch
  gemm_gate<<<dim3(16, 32), 256, 0, stream>>>(x_bf, qkr_b, gQ, gK, gV, Aq, Ak, Av, 2048);

  // [Q;K] = Acat * qk_write (M=8192,N=2048,K=512)  ++  Vt = vwT * Av^T (M=2048,N=4096)
  gemm_qkv<<<1536, 256, 0, stream>>>(Aq, qkwT, Qb, vwT, Av, Vt);

  // attention -> AO (bf16, [4096][2048])
  attn_kernel<<<dim3(32, 32), 256, 0, stream>>>(Qb, Kb, Vt, AO);

  // out = AO * W_O * 1/keep^2   (f32 out)
  gemm_bt<true, 128, 128><<<dim3(16, 32), 256, 0, stream>>>(AO, woT, out, 2048, 2048,
                                                            1.2345679012345678f);
}